// Round 4
// baseline (926.136 us; speedup 1.0000x reference)
//
#include <hip/hip_runtime.h>
#include <hip/hip_bf16.h>

#define B 1024
#define H 1024
#define T 512
#define NUM 44
#define IN 128
#define AK (IN + 2 * H)   // 2176
#define XC (IN + H)       // 1152
#define G4 (4 * H)        // 4096
#define BH ((size_t)B * H)

typedef __attribute__((ext_vector_type(8))) short s16x8;
typedef __attribute__((ext_vector_type(4))) float f32x4;

__device__ __forceinline__ unsigned short f2bf(float f) {
    unsigned u = __float_as_uint(f);
    unsigned r = (u + 0x7fffu + ((u >> 16) & 1u)) >> 16;
    return (unsigned short)r;
}
__device__ __forceinline__ float bf2f(unsigned short u) {
    return __uint_as_float(((unsigned)u) << 16);
}

__device__ __forceinline__ void gload16(const ushort* g, ushort* l) {
    __builtin_amdgcn_global_load_lds(
        (const __attribute__((address_space(1))) void*)g,
        (__attribute__((address_space(3))) void*)l,
        16, 0, 0);
}

#define TM 128
#define TN 128
#define TK 32

// ================= fat MFMA mainloop (128x128 tile, 4 waves of 64x64) =================
__device__ __forceinline__ void mainloop_fat(
    const ushort* __restrict__ X, const ushort* __restrict__ W,
    int kbeg, int kend, int ldx, int ldw, int m0, int n0,
    ushort (*As)[TK], ushort (*Bs)[TK], f32x4 (*acc)[4])
{
    const int tid = threadIdx.x;
    const int lane = tid & 63;
    const int wid = tid >> 6;
    const int wm = wid >> 1, wn = wid & 1;
    const int srow = wid * 32 + (lane >> 2);
    const int skc  = (lane & 3) * 8;

    for (int k0 = kbeg; k0 < kend; k0 += TK) {
        gload16(X + (size_t)(m0 + srow) * ldx + k0 + skc,      &As[wid * 32][0]);
        gload16(X + (size_t)(m0 + srow + 16) * ldx + k0 + skc, &As[wid * 32 + 16][0]);
        gload16(W + (size_t)(n0 + srow) * ldw + k0 + skc,      &Bs[wid * 32][0]);
        gload16(W + (size_t)(n0 + srow + 16) * ldw + k0 + skc, &Bs[wid * 32 + 16][0]);
        __syncthreads();
        s16x8 a[4], b[4];
        #pragma unroll
        for (int m = 0; m < 4; ++m)
            a[m] = *(const s16x8*)&As[wm * 64 + m * 16 + (lane & 15)][(lane >> 4) * 8];
        #pragma unroll
        for (int n = 0; n < 4; ++n)
            b[n] = *(const s16x8*)&Bs[wn * 64 + n * 16 + (lane & 15)][(lane >> 4) * 8];
        #pragma unroll
        for (int m = 0; m < 4; ++m)
            #pragma unroll
            for (int n = 0; n < 4; ++n)
                acc[m][n] = __builtin_amdgcn_mfma_f32_16x16x32_bf16(a[m], b[n], acc[m][n], 0, 0, 0);
        __syncthreads();
    }
}

// ================= logits GEMM (split-K): Cf[z] = X@W^T chunk =================
__global__ __launch_bounds__(256) void gemm_logits_kernel(
    const ushort* __restrict__ X, const ushort* __restrict__ W,
    float* __restrict__ Cf, int Kchunk)
{
    __shared__ ushort As[TM][TK];
    __shared__ ushort Bs[TM][TK];
    f32x4 acc[4][4] = {};
    int kbeg = blockIdx.z * Kchunk;
    int m0 = blockIdx.y * TM, n0 = blockIdx.x * TN;
    mainloop_fat(X, W, kbeg, kbeg + Kchunk, AK, AK, m0, n0, As, Bs, acc);
    const int lane = threadIdx.x & 63;
    const int wid = threadIdx.x >> 6;
    const int wm = wid >> 1, wn = wid & 1;
    float* out = Cf + (size_t)blockIdx.z * B * T;
    #pragma unroll
    for (int m = 0; m < 4; ++m)
        #pragma unroll
        for (int n = 0; n < 4; ++n) {
            int col = n0 + wn * 64 + n * 16 + (lane & 15);
            #pragma unroll
            for (int j = 0; j < 4; ++j) {
                int row = m0 + wm * 64 + m * 16 + (lane >> 4) * 4 + j;
                out[(size_t)row * T + col] = acc[m][n][j];
            }
        }
}

// ================= fused GEMM + LSTM: gates = X@W^T + CinBf + bias -> h,c =================
// W rows are gate-interleaved: col c -> gate (c&3), unit j (c>>2).
__global__ __launch_bounds__(256) void gemm_lstm_kernel(
    const ushort* __restrict__ X, const ushort* __restrict__ W,
    const ushort* __restrict__ CinBf,
    const float* __restrict__ biasf,       // permuted fused bias (g1), or null
    const float* __restrict__ b1, const float* __restrict__ b2, // standard-order biases (g2)
    const float* __restrict__ c_in, float* __restrict__ h_out, float* __restrict__ c_out,
    ushort* __restrict__ h_bf, int K)
{
    __shared__ ushort As[TM][TK];
    __shared__ ushort Bs[TM][TK];
    f32x4 acc[4][4] = {};
    int m0 = blockIdx.y * TM, n0 = blockIdx.x * TN;
    mainloop_fat(X, W, 0, K, K, K, m0, n0, As, Bs, acc);

    const int lane = threadIdx.x & 63;
    const int wid = threadIdx.x >> 6;
    const int wm = wid >> 1, wn = wid & 1;
    const int q = lane & 3;

    #pragma unroll
    for (int m = 0; m < 4; ++m) {
        #pragma unroll
        for (int n = 0; n < 4; ++n) {
            int col = n0 + wn * 64 + n * 16 + (lane & 15);
            int j = col >> 2;
            float badd = biasf ? biasf[col]
                               : (b1[(col & 3) * H + j] + b2[(col & 3) * H + j]);
            #pragma unroll
            for (int jj = 0; jj < 4; ++jj) {
                int row = m0 + wm * 64 + m * 16 + (lane >> 4) * 4 + jj;
                float pre = acc[m][n][jj] + badd + bf2f(CinBf[(size_t)row * G4 + col]);
                float f1 = __shfl_xor(pre, 1, 64);
                float f2 = __shfl_xor(pre, 2, 64);
                float f3 = __shfl_xor(pre, 3, 64);
                float gi = q == 0 ? pre : q == 1 ? f1 : q == 2 ? f2 : f3;
                float gf = q == 0 ? f1 : q == 1 ? pre : q == 2 ? f3 : f2;
                float gg = q == 0 ? f2 : q == 1 ? f3 : q == 2 ? pre : f1;
                float go = q == 0 ? f3 : q == 1 ? f2 : q == 2 ? f1 : pre;
                float si = 1.0f / (1.0f + expf(-gi));
                float sf = 1.0f / (1.0f + expf(-gf));
                float so = 1.0f / (1.0f + expf(-go));
                float c = sf * c_in[(size_t)row * H + j] + si * tanhf(gg);
                float h = so * tanhf(c);
                if (q == 0) {
                    h_out[(size_t)row * H + j] = h;
                    c_out[(size_t)row * H + j] = c;
                    if (h_bf) h_bf[(size_t)row * H + j] = f2bf(h);
                }
            }
        }
    }
}

// ================= preamble: all converts + transpose + bias_f + build =================
#define S0 2048           // h0 flat (524288 f4)
#define S1 (S0 + 1088)    // attn_w flat (278528 f4)
#define S2 (S1 + 512)     // wih0 perm (131072 f4, row 32 f4)
#define S3 (S2 + 4096)    // whh0 perm (1048576 f4, row 256 f4)
#define S4 (S3 + 4096)    // wih1 perm
#define S5 (S4 + 4096)    // whh1 perm
#define S6 (S5 + 576)     // comb_w transpose (147456 scalar)
#define S7 (S6 + 16)      // bias_f (4096)
#define S8 (S7 + 1024)    // build attn_in

__global__ __launch_bounds__(256) void preamble_kernel(
    const float* __restrict__ h0, const float* __restrict__ attn_w,
    const float* __restrict__ w_ih0, const float* __restrict__ w_hh0,
    const float* __restrict__ w_ih1, const float* __restrict__ w_hh1,
    const float* __restrict__ comb_w, const float* __restrict__ comb_b,
    const float* __restrict__ b_ih0, const float* __restrict__ b_hh0,
    const float* __restrict__ x, const int* __restrict__ x_emb,
    const float* __restrict__ c0,
    const float* __restrict__ e0, const float* __restrict__ e1,
    const float* __restrict__ e2, const float* __restrict__ e3,
    ushort* __restrict__ h0_bf, ushort* __restrict__ attn_w_bf,
    ushort* __restrict__ wih0p, ushort* __restrict__ whh0p,
    ushort* __restrict__ wih1p, ushort* __restrict__ whh1p,
    ushort* __restrict__ comb_wT, float* __restrict__ biasf,
    ushort* __restrict__ attn_in, ushort* __restrict__ xctx)
{
    const int bid = blockIdx.x;
    const int tid = threadIdx.x;
    __shared__ float cb[IN];

    if (bid < S5) {
        const float* src; ushort* dst; int f;
        if (bid < S0)      { f = bid * 256 + tid;        src = h0;     dst = h0_bf;
                             float4 v = ((const float4*)src)[f];
                             ushort4 o = {f2bf(v.x), f2bf(v.y), f2bf(v.z), f2bf(v.w)};
                             ((ushort4*)dst)[f] = o; return; }
        if (bid < S1)      { f = (bid - S0) * 256 + tid; src = attn_w; dst = attn_w_bf;
                             float4 v = ((const float4*)src)[f];
                             ushort4 o = {f2bf(v.x), f2bf(v.y), f2bf(v.z), f2bf(v.w)};
                             ((ushort4*)dst)[f] = o; return; }
        int srcidx;
        if (bid < S2) {  // wih0 perm, row = 32 f4
            f = (bid - S1) * 256 + tid;
            int r = f >> 5, c = f & 31;
            srcidx = (((r & 3) << 10) + (r >> 2)) * 32 + c;
            src = w_ih0; dst = wih0p;
        } else {
            if (bid < S3)      { f = (bid - S2) * 256 + tid; src = w_hh0; dst = whh0p; }
            else if (bid < S4) { f = (bid - S3) * 256 + tid; src = w_ih1; dst = wih1p; }
            else               { f = (bid - S4) * 256 + tid; src = w_hh1; dst = whh1p; }
            int r = f >> 8, c = f & 255;
            srcidx = (((r & 3) << 10) + (r >> 2)) * 256 + c;
        }
        float4 v = ((const float4*)src)[srcidx];
        ushort4 o = {f2bf(v.x), f2bf(v.y), f2bf(v.z), f2bf(v.w)};
        ((ushort4*)dst)[f] = o;
    } else if (bid < S6) {
        int e = (bid - S5) * 256 + tid;      // comb_wT[j*128+k] = comb_w[k][j]
        int j = e >> 7, k = e & 127;
        comb_wT[e] = f2bf(comb_w[(size_t)k * XC + j]);
    } else if (bid < S7) {
        for (int i = tid; i < IN; i += 256) cb[i] = comb_b[i];
        __syncthreads();
        int p = (bid - S6) * 256 + tid;      // permuted out index
        int srow = (p & 3) * 1024 + (p >> 2);
        float s = b_ih0[srow] + b_hh0[srow];
        const float* row = w_ih0 + (size_t)srow * IN;
        #pragma unroll 8
        for (int i = 0; i < IN; ++i) s += row[i] * cb[i];
        biasf[p] = s;
    } else {
        int b = bid - S7;
        int id0 = x_emb[b * 4 + 0];
        int id1 = x_emb[b * 4 + 1];
        int id2 = x_emb[b * 4 + 2];
        int id3 = x_emb[b * 4 + 3];
        ushort* dst = attn_in + (size_t)b * AK;
        for (int j = tid; j < AK; j += 256) {
            float v;
            if (j < 44)        v = x[b * NUM + j];
            else if (j < 108)  v = e0[id0 * 64 + (j - 44)];
            else if (j < 116)  v = e1[id1 * 8 + (j - 108)];
            else if (j < 124)  v = e2[id2 * 8 + (j - 116)];
            else if (j < 128)  v = e3[id3 * 4 + (j - 124)];
            else if (j < 1152) v = h0[b * H + (j - 128)];
            else               v = c0[b * H + (j - 1152)];
            unsigned short bf = f2bf(v);
            dst[j] = bf;
            if (j < IN) xctx[(size_t)b * XC + j] = bf;
        }
    }
}

// ================= MEGA: interleaved ctx-stream + slim GEMMs =================
// bid < 2048: even -> ctx (id=bid>>1), odd -> gemm (id=bid>>1); bid >= 2048: gemm (1024+bid-2048)
// gemm ids: [0,512) hh0, [512,1024) hh1, [1024,1600) W_f.  Slim tile: 128x64, wave 64x32.
__global__ __launch_bounds__(256, 4) void mega_kernel(
    const ushort* __restrict__ h0_bf, const ushort* __restrict__ whh0p,
    const ushort* __restrict__ whh1p, ushort* __restrict__ g1buf, ushort* __restrict__ g2buf,
    const ushort* __restrict__ wih0p, const ushort* __restrict__ comb_wT,
    ushort* __restrict__ W_f,
    const float* __restrict__ logits_p, const float* __restrict__ attn_b,
    float* __restrict__ aw_out, const float* __restrict__ enc, ushort* __restrict__ xctx)
{
    __shared__ union {
        struct { ushort As[128][TK]; ushort Bs[64][TK]; } g;
        struct { float w[T]; float red[8]; } c;
    } sh;

    const int bid = blockIdx.x;
    const int tid = threadIdx.x;
    bool is_ctx; int rid;
    if (bid < 2048) { is_ctx = !(bid & 1); rid = bid >> 1; }
    else            { is_ctx = false;      rid = 1024 + (bid - 2048); }

    if (is_ctx) {
        const int b = rid;
        float v0 = attn_b[tid], v1 = attn_b[tid + 256];
        #pragma unroll
        for (int z = 0; z < 4; ++z) {
            const float* lp = logits_p + (size_t)z * B * T + (size_t)b * T;
            v0 += lp[tid];
            v1 += lp[tid + 256];
        }
        float m = fmaxf(v0, v1);
        #pragma unroll
        for (int off = 32; off > 0; off >>= 1) m = fmaxf(m, __shfl_down(m, off, 64));
        if ((tid & 63) == 0) sh.c.red[tid >> 6] = m;
        __syncthreads();
        m = fmaxf(fmaxf(sh.c.red[0], sh.c.red[1]), fmaxf(sh.c.red[2], sh.c.red[3]));
        float e0 = expf(v0 - m), e1 = expf(v1 - m);
        float s = e0 + e1;
        #pragma unroll
        for (int off = 32; off > 0; off >>= 1) s += __shfl_down(s, off, 64);
        if ((tid & 63) == 0) sh.c.red[4 + (tid >> 6)] = s;
        __syncthreads();
        s = sh.c.red[4] + sh.c.red[5] + sh.c.red[6] + sh.c.red[7];
        float inv = 1.0f / s;
        float w0 = e0 * inv, w1 = e1 * inv;
        sh.c.w[tid] = w0;
        sh.c.w[tid + 256] = w1;
        aw_out[(size_t)b * T + tid]       = w0;
        aw_out[(size_t)b * T + tid + 256] = w1;
        __syncthreads();

        const float* p = enc + (size_t)b * H + tid * 4;
        float4 acc = {0.f, 0.f, 0.f, 0.f};
        #pragma unroll 8
        for (int t = 0; t < T; ++t) {
            float4 v = *(const float4*)(p + (size_t)t * B * H);
            float sw = sh.c.w[t];
            acc.x += sw * v.x; acc.y += sw * v.y; acc.z += sw * v.z; acc.w += sw * v.w;
        }
        ushort4 o = {f2bf(acc.x), f2bf(acc.y), f2bf(acc.z), f2bf(acc.w)};
        *(ushort4*)(xctx + (size_t)b * XC + IN + tid * 4) = o;
    } else {
        const ushort *X, *W; ushort* Cb;
        int K, ldx, ldw, ldc, m0, n0;
        if (rid < 1024) {
            int layer = rid >> 9, t = rid & 511;
            m0 = (t >> 6) * 128; n0 = (t & 63) * 64;
            X = h0_bf + (size_t)layer * BH; W = layer ? whh1p : whh0p;
            Cb = layer ? g2buf : g1buf;
            K = H; ldx = H; ldw = H; ldc = G4;
        } else {
            int t = rid - 1024;
            m0 = (t / 18) * 128; n0 = (t % 18) * 64;
            X = wih0p; W = comb_wT; Cb = W_f;
            K = IN; ldx = IN; ldw = IN; ldc = XC;
        }
        const int lane = tid & 63;
        const int wid = tid >> 6;
        const int wm = wid >> 1, wn = wid & 1;
        f32x4 acc[4][2] = {};

        for (int k0 = 0; k0 < K; k0 += TK) {
            gload16(X + (size_t)(m0 + wid * 16 + (lane >> 2)) * ldx + k0 + (lane & 3) * 8,
                    &sh.g.As[wid * 16][0]);
            gload16(X + (size_t)(m0 + 64 + wid * 16 + (lane >> 2)) * ldx + k0 + (lane & 3) * 8,
                    &sh.g.As[64 + wid * 16][0]);
            gload16(W + (size_t)(n0 + wid * 16 + (lane >> 2)) * ldw + k0 + (lane & 3) * 8,
                    &sh.g.Bs[wid * 16][0]);
            __syncthreads();
            s16x8 a[4], b[2];
            #pragma unroll
            for (int m = 0; m < 4; ++m)
                a[m] = *(const s16x8*)&sh.g.As[wm * 64 + m * 16 + (lane & 15)][(lane >> 4) * 8];
            #pragma unroll
            for (int n = 0; n < 2; ++n)
                b[n] = *(const s16x8*)&sh.g.Bs[wn * 32 + n * 16 + (lane & 15)][(lane >> 4) * 8];
            #pragma unroll
            for (int m = 0; m < 4; ++m)
                #pragma unroll
                for (int n = 0; n < 2; ++n)
                    acc[m][n] = __builtin_amdgcn_mfma_f32_16x16x32_bf16(a[m], b[n], acc[m][n], 0, 0, 0);
            __syncthreads();
        }

        #pragma unroll
        for (int m = 0; m < 4; ++m)
            #pragma unroll
            for (int n = 0; n < 2; ++n) {
                int col = n0 + wn * 32 + n * 16 + (lane & 15);
                #pragma unroll
                for (int jj = 0; jj < 4; ++jj) {
                    int row = m0 + wm * 64 + m * 16 + (lane >> 4) * 4 + jj;
                    Cb[(size_t)row * ldc + col] = f2bf(acc[m][n][jj]);
                }
            }
    }
}

// ================= pred =================
__global__ __launch_bounds__(256) void pred_kernel(
    const float* __restrict__ h2, const float* __restrict__ pw,
    const float* __restrict__ pb, float* __restrict__ out)
{
    int b = blockIdx.x;
    const float* row = h2 + (size_t)b * H;
    float s = 0.f;
    for (int j = threadIdx.x; j < H; j += 256) s += row[j] * pw[j];
    #pragma unroll
    for (int off = 32; off > 0; off >>= 1) s += __shfl_down(s, off, 64);
    __shared__ float sm[4];
    if ((threadIdx.x & 63) == 0) sm[threadIdx.x >> 6] = s;
    __syncthreads();
    if (threadIdx.x == 0) out[b] = sm[0] + sm[1] + sm[2] + sm[3] + pb[0];
}

extern "C" void kernel_launch(void* const* d_in, const int* in_sizes, int n_in,
                              void* d_out, int out_size, void* d_ws, size_t ws_size,
                              hipStream_t stream) {
    (void)in_sizes; (void)n_in; (void)out_size; (void)ws_size;
    const float* x      = (const float*)d_in[0];
    const int*   x_emb  = (const int*)d_in[1];
    const float* h0     = (const float*)d_in[2];
    const float* c0     = (const float*)d_in[3];
    const float* enc    = (const float*)d_in[4];
    const float* emb0   = (const float*)d_in[5];
    const float* emb1   = (const float*)d_in[6];
    const float* emb2   = (const float*)d_in[7];
    const float* emb3   = (const float*)d_in[8];
    const float* attn_w = (const float*)d_in[9];
    const float* attn_b = (const float*)d_in[10];
    const float* comb_w = (const float*)d_in[11];
    const float* comb_b = (const float*)d_in[12];
    const float* w_ih0  = (const float*)d_in[13];
    const float* w_hh0  = (const float*)d_in[14];
    const float* b_ih0  = (const float*)d_in[15];
    const float* b_hh0  = (const float*)d_in[16];
    const float* w_ih1  = (const float*)d_in[17];
    const float* w_hh1  = (const float*)d_in[18];
    const float* b_ih1  = (const float*)d_in[19];
    const float* b_hh1  = (const float*)d_in[20];
    const float* pred_w = (const float*)d_in[21];
    const float* pred_b = (const float*)d_in[22];

    float* out = (float*)d_out;
    float* h1_out = out + 1024;
    float* h2_out = out + 1024 + BH;
    float* c1_out = out + 1024 + 2 * BH;
    float* c2_out = out + 1024 + 3 * BH;
    float* aw_out = out + 1024 + 4 * BH;

    char* w = (char*)d_ws;
    ushort* attn_in_bf = (ushort*)w;  w += (size_t)B * AK * 2;
    ushort* h0_bf      = (ushort*)w;  w += (size_t)2 * BH * 2;
    ushort* attn_w_bf  = (ushort*)w;  w += (size_t)T * AK * 2;
    ushort* wih0p      = (ushort*)w;  w += (size_t)G4 * IN * 2;
    ushort* whh0p      = (ushort*)w;  w += (size_t)G4 * H * 2;
    ushort* wih1p      = (ushort*)w;  w += (size_t)G4 * H * 2;
    ushort* whh1p      = (ushort*)w;  w += (size_t)G4 * H * 2;
    ushort* comb_wT    = (ushort*)w;  w += (size_t)XC * IN * 2;
    ushort* W_f        = (ushort*)w;  w += (size_t)G4 * XC * 2;
    float*  bias_f     = (float*)w;   w += (size_t)G4 * 4;
    ushort* xctx_bf    = (ushort*)w;  w += (size_t)B * XC * 2;
    ushort* h1_bf      = (ushort*)w;  w += (size_t)BH * 2;
    float*  logits_p   = (float*)w;   w += (size_t)4 * B * T * 4;
    ushort* g1buf      = (ushort*)w;  w += (size_t)B * G4 * 2;
    ushort* g2buf      = (ushort*)w;  w += (size_t)B * G4 * 2;
    // total ~76.5 MB

    preamble_kernel<<<S8, 256, 0, stream>>>(
        h0, attn_w, w_ih0, w_hh0, w_ih1, w_hh1, comb_w, comb_b, b_ih0, b_hh0,
        x, x_emb, c0, emb0, emb1, emb2, emb3,
        h0_bf, attn_w_bf, wih0p, whh0p, wih1p, whh1p, comb_wT, bias_f,
        attn_in_bf, xctx_bf);

    // logits partials: 1024x512, K=2176 split 4x544
    gemm_logits_kernel<<<dim3(T / TN, B / TM, 4), 256, 0, stream>>>(
        attn_in_bf, attn_w_bf, logits_p, 544);

    // MEGA: interleaved [ctx+softmax stream] with [hh0 | hh1 | W_f] slim GEMMs
    mega_kernel<<<2624, 256, 0, stream>>>(
        h0_bf, whh0p, whh1p, g1buf, g2buf,
        wih0p, comb_wT, W_f,
        logits_p, attn_b, aw_out, enc, xctx_bf);

    // g1 = xctx @ W_f^T + g1buf + bias_f -> LSTM -> h1, c1, h1_bf   (K=1152)
    gemm_lstm_kernel<<<dim3(G4 / TN, B / TM), 256, 0, stream>>>(
        xctx_bf, W_f, g1buf, bias_f, nullptr, nullptr,
        c0, h1_out, c1_out, h1_bf, XC);

    // g2 = h1 @ w_ih1^T + g2buf + b_ih1 + b_hh1 -> LSTM -> h2, c2   (K=1024)
    gemm_lstm_kernel<<<dim3(G4 / TN, B / TM), 256, 0, stream>>>(
        h1_bf, wih1p, g2buf, nullptr, b_ih1, b_hh1,
        c0 + BH, h2_out, c2_out, nullptr, H);

    pred_kernel<<<1024, 256, 0, stream>>>(h2_out, pred_w, pred_b, out);
}

// Round 5
// 661.890 us; speedup vs baseline: 1.3992x; 1.3992x over previous
//
#include <hip/hip_runtime.h>
#include <hip/hip_bf16.h>

#define B 1024
#define H 1024
#define T 512
#define NUM 44
#define IN 128
#define AK (IN + 2 * H)   // 2176
#define XC (IN + H)       // 1152
#define G4 (4 * H)        // 4096

typedef __attribute__((ext_vector_type(8))) short s16x8;
typedef __attribute__((ext_vector_type(4))) float f32x4;

__device__ __forceinline__ unsigned short f2bf(float f) {
    unsigned u = __float_as_uint(f);
    unsigned r = (u + 0x7fffu + ((u >> 16) & 1u)) >> 16;
    return (unsigned short)r;
}

__device__ __forceinline__ void gload16(const ushort* g, ushort* l) {
    __builtin_amdgcn_global_load_lds(
        (const __attribute__((address_space(1))) void*)g,
        (__attribute__((address_space(3))) void*)l,
        16, 0, 0);
}

#define TM 128
#define TN 128
#define TK 32

// ---------------- shared GEMM tile core (single phase, C = X@W^T [+Cin][+b1][+b2]) ----------------
__device__ __forceinline__ void gemm_core(
    const ushort* __restrict__ X, const ushort* __restrict__ W,
    const float* __restrict__ bias1, const float* __restrict__ bias2,
    const float* __restrict__ Cin, float* __restrict__ Cf, ushort* __restrict__ Cb,
    int kbeg, int kend, int ldx, int ldw, int ldc,
    int m0, int n0, ushort (*As)[TK], ushort (*Bs)[TK])
{
    const int tid = threadIdx.x;
    const int lane = tid & 63;
    const int wid = tid >> 6;
    const int wm = wid >> 1, wn = wid & 1;
    const int srow = wid * 32 + (lane >> 2);
    const int skc  = (lane & 3) * 8;

    f32x4 acc[4][4] = {};

    for (int k0 = kbeg; k0 < kend; k0 += TK) {
        gload16(X + (size_t)(m0 + srow) * ldx + k0 + skc,      &As[wid * 32][0]);
        gload16(X + (size_t)(m0 + srow + 16) * ldx + k0 + skc, &As[wid * 32 + 16][0]);
        gload16(W + (size_t)(n0 + srow) * ldw + k0 + skc,      &Bs[wid * 32][0]);
        gload16(W + (size_t)(n0 + srow + 16) * ldw + k0 + skc, &Bs[wid * 32 + 16][0]);
        __syncthreads();

        s16x8 a[4], b[4];
        #pragma unroll
        for (int m = 0; m < 4; ++m)
            a[m] = *(const s16x8*)&As[wm * 64 + m * 16 + (lane & 15)][(lane >> 4) * 8];
        #pragma unroll
        for (int n = 0; n < 4; ++n)
            b[n] = *(const s16x8*)&Bs[wn * 64 + n * 16 + (lane & 15)][(lane >> 4) * 8];
        #pragma unroll
        for (int m = 0; m < 4; ++m)
            #pragma unroll
            for (int n = 0; n < 4; ++n)
                acc[m][n] = __builtin_amdgcn_mfma_f32_16x16x32_bf16(a[m], b[n], acc[m][n], 0, 0, 0);
        __syncthreads();
    }

    #pragma unroll
    for (int m = 0; m < 4; ++m) {
        #pragma unroll
        for (int n = 0; n < 4; ++n) {
            int col = n0 + wn * 64 + n * 16 + (lane & 15);
            float badd = (bias1 ? bias1[col] : 0.f) + (bias2 ? bias2[col] : 0.f);
            #pragma unroll
            for (int j = 0; j < 4; ++j) {
                int row = m0 + wm * 64 + m * 16 + (lane >> 4) * 4 + j;
                float v = acc[m][n][j] + badd;
                if (Cin) v += Cin[(size_t)row * ldc + col];
                if (Cf) Cf[(size_t)row * ldc + col] = v;
                if (Cb) Cb[(size_t)row * ldc + col] = f2bf(v);
            }
        }
    }
}

// ---------------- standalone GEMM (with optional split-K via blockIdx.z) ----------------
__global__ __launch_bounds__(256) void gemm_kernel(
    const ushort* __restrict__ X, const ushort* __restrict__ W,
    const float* __restrict__ bias1, const float* __restrict__ bias2,
    const float* __restrict__ Cin, float* __restrict__ Cf, ushort* __restrict__ Cb,
    int Kchunk, int ldx, int ldw, int ldc, size_t Czstride)
{
    __shared__ ushort As[TM][TK];
    __shared__ ushort Bs[TN][TK];
    int kbeg = blockIdx.z * Kchunk;
    gemm_core(X, W, bias1, bias2, Cin,
              Cf ? Cf + (size_t)blockIdx.z * Czstride : nullptr, Cb,
              kbeg, kbeg + Kchunk, ldx, ldw, ldc,
              blockIdx.y * TM, blockIdx.x * TN, As, Bs);
}

// ---------------- merged f32 -> bf16 converts (6 segments, float4 units) ----------------
#define CN0 524288   // h0: 2*B*H/4
#define CN1 278528   // attn_w: T*AK/4
#define CN2 131072   // w_ih0: G4*IN/4
#define CN3 1048576  // w_hh0: G4*H/4
#define CN4 1048576  // w_ih1
#define CN5 1048576  // w_hh1
#define CNT (CN0+CN1+CN2+CN3+CN4+CN5)

__global__ __launch_bounds__(256) void convert_all_kernel(
    const float* __restrict__ s0, const float* __restrict__ s1, const float* __restrict__ s2,
    const float* __restrict__ s3, const float* __restrict__ s4, const float* __restrict__ s5,
    ushort* __restrict__ d0, ushort* __restrict__ d1, ushort* __restrict__ d2,
    ushort* __restrict__ d3, ushort* __restrict__ d4, ushort* __restrict__ d5)
{
    int i = blockIdx.x * 256 + threadIdx.x;
    const float* s; ushort* d;
    if (i < CN0) { s = s0; d = d0; }
    else if ((i -= CN0) < CN1) { s = s1; d = d1; }
    else if ((i -= CN1) < CN2) { s = s2; d = d2; }
    else if ((i -= CN2) < CN3) { s = s3; d = d3; }
    else if ((i -= CN3) < CN4) { s = s4; d = d4; }
    else if ((i -= CN4) < CN5) { s = s5; d = d5; }
    else return;
    float4 v = ((const float4*)s)[i];
    ushort4 o;
    o.x = f2bf(v.x); o.y = f2bf(v.y); o.z = f2bf(v.z); o.w = f2bf(v.w);
    ((ushort4*)d)[i] = o;
}

// ---------------- comb_w (128 x 1152) -> transposed bf16 (1152 x 128) ----------------
__global__ __launch_bounds__(256) void transpose_combw_kernel(
    const float* __restrict__ comb_w, ushort* __restrict__ outT)
{
    int idx = blockIdx.x * 256 + threadIdx.x;   // 0 .. 147455
    int j = idx >> 7;      // 0..1151
    int k = idx & 127;     // 0..127
    outT[idx] = f2bf(comb_w[(size_t)k * XC + j]);
}

// ---------------- bias_f[i] = w_ih0[i]·comb_b + b_ih0[i] + b_hh0[i] ----------------
__global__ __launch_bounds__(256) void bias_f_kernel(
    const float* __restrict__ w_ih0, const float* __restrict__ comb_b,
    const float* __restrict__ b_ih0, const float* __restrict__ b_hh0,
    float* __restrict__ biasf)
{
    __shared__ float cb[IN];
    int i = blockIdx.x * 256 + threadIdx.x;     // 0..4095
    for (int j = threadIdx.x; j < IN; j += 256) cb[j] = comb_b[j];
    __syncthreads();
    float s = b_ih0[i] + b_hh0[i];
    const float* row = w_ih0 + (size_t)i * IN;
    #pragma unroll 8
    for (int j = 0; j < IN; ++j) s += row[j] * cb[j];
    biasf[i] = s;
}

// ---------------- build attn_in (bf16) + xctx[:, :128] ----------------
__global__ __launch_bounds__(256) void build_attn_in_kernel(
    const float* __restrict__ x, const int* __restrict__ x_emb,
    const float* __restrict__ h0, const float* __restrict__ c0,
    const float* __restrict__ e0, const float* __restrict__ e1,
    const float* __restrict__ e2, const float* __restrict__ e3,
    ushort* __restrict__ attn_in, ushort* __restrict__ xctx)
{
    int b = blockIdx.x;
    int id0 = x_emb[b * 4 + 0];
    int id1 = x_emb[b * 4 + 1];
    int id2 = x_emb[b * 4 + 2];
    int id3 = x_emb[b * 4 + 3];
    ushort* dst = attn_in + (size_t)b * AK;
    for (int j = threadIdx.x; j < AK; j += 256) {
        float v;
        if (j < 44)        v = x[b * NUM + j];
        else if (j < 108)  v = e0[id0 * 64 + (j - 44)];
        else if (j < 116)  v = e1[id1 * 8 + (j - 108)];
        else if (j < 124)  v = e2[id2 * 8 + (j - 116)];
        else if (j < 128)  v = e3[id3 * 4 + (j - 124)];
        else if (j < 1152) v = h0[b * H + (j - 128)];
        else               v = c0[b * H + (j - 1152)];
        unsigned short bf = f2bf(v);
        dst[j] = bf;
        if (j < IN) xctx[(size_t)b * XC + j] = bf;
    }
}

// ---------------- MEGA: interleaved [ctx(+softmax) stream] with [hh0 | hh1 | W_f] GEMMs ----------------
// 1824 blocks. Bresenham interleave: 800 GEMM blocks spread uniformly among 1024 ctx blocks
// so streaming and MFMA blocks are co-resident from dispatch 0 (R3 ran them in phases -> no overlap).
// gemm rid: [0,256) hh0, [256,512) hh1, [512,800) W_f.
__global__ __launch_bounds__(256) void mega_kernel(
    const ushort* __restrict__ h0_bf, const ushort* __restrict__ whh0_bf,
    const ushort* __restrict__ whh1_bf, float* __restrict__ g1buf, float* __restrict__ g2buf,
    const ushort* __restrict__ wih0_bf, const ushort* __restrict__ comb_wT_bf,
    ushort* __restrict__ W_f_bf,
    const float* __restrict__ logits_part, const float* __restrict__ attn_b,
    float* __restrict__ aw_out, const float* __restrict__ enc, ushort* __restrict__ xctx)
{
    __shared__ union {
        struct { ushort As[TM][TK]; ushort Bs[TN][TK]; } g;
        struct { float w[T]; float red[8]; } c;
    } sh;

    const int bid = blockIdx.x;
    const int gid_before = (int)(((long)bid * 800) / 1824);
    const int gid_after  = (int)(((long)(bid + 1) * 800) / 1824);
    const bool is_gemm = gid_after > gid_before;

    if (is_gemm) {
        const int rid = gid_before;
        if (rid < 512) {
            // hh GEMM: g_hh = h0[layer] @ w_hh^T   (1024 x 4096, K=1024)
            int layer = rid >> 8;
            int t = rid & 255;
            int m0 = (t >> 5) * TM;
            int n0 = (t & 31) * TN;
            gemm_core(h0_bf + (size_t)layer * B * H, layer ? whh1_bf : whh0_bf,
                      nullptr, nullptr, nullptr, layer ? g2buf : g1buf, nullptr,
                      0, H, H, H, G4, m0, n0, sh.g.As, sh.g.Bs);
        } else {
            // W_f = w_ih0 @ comb_w  (4096 x 1152, K=128) -> bf16
            int t = rid - 512;
            int m0 = (t / 9) * TM;
            int n0 = (t % 9) * TN;
            gemm_core(wih0_bf, comb_wT_bf, nullptr, nullptr, nullptr, nullptr, W_f_bf,
                      0, IN, IN, IN, XC, m0, n0, sh.g.As, sh.g.Bs);
        }
    } else {
        // ctx + softmax for row b
        int b = bid - gid_before;
        int tid = threadIdx.x;
        float v0 = attn_b[tid], v1 = attn_b[tid + 256];
        #pragma unroll
        for (int z = 0; z < 4; ++z) {
            const float* lp = logits_part + (size_t)z * B * T + (size_t)b * T;
            v0 += lp[tid];
            v1 += lp[tid + 256];
        }
        float m = fmaxf(v0, v1);
        #pragma unroll
        for (int off = 32; off > 0; off >>= 1) m = fmaxf(m, __shfl_down(m, off, 64));
        if ((tid & 63) == 0) sh.c.red[tid >> 6] = m;
        __syncthreads();
        m = fmaxf(fmaxf(sh.c.red[0], sh.c.red[1]), fmaxf(sh.c.red[2], sh.c.red[3]));
        float e0 = expf(v0 - m), e1 = expf(v1 - m);
        float s = e0 + e1;
        #pragma unroll
        for (int off = 32; off > 0; off >>= 1) s += __shfl_down(s, off, 64);
        if ((tid & 63) == 0) sh.c.red[4 + (tid >> 6)] = s;
        __syncthreads();
        s = sh.c.red[4] + sh.c.red[5] + sh.c.red[6] + sh.c.red[7];
        float inv = 1.0f / s;
        float w0 = e0 * inv, w1 = e1 * inv;
        sh.c.w[tid] = w0;
        sh.c.w[tid + 256] = w1;
        aw_out[(size_t)b * T + tid]       = w0;
        aw_out[(size_t)b * T + tid + 256] = w1;
        __syncthreads();

        int h0i = tid * 4;
        const float* p = enc + (size_t)b * H + h0i;
        float4 acc = {0.f, 0.f, 0.f, 0.f};
        #pragma unroll 8
        for (int t = 0; t < T; ++t) {
            float4 v = *(const float4*)(p + (size_t)t * B * H);
            float sw = sh.c.w[t];
            acc.x += sw * v.x; acc.y += sw * v.y; acc.z += sw * v.z; acc.w += sw * v.w;
        }
        ushort4 o;
        o.x = f2bf(acc.x); o.y = f2bf(acc.y); o.z = f2bf(acc.z); o.w = f2bf(acc.w);
        *(ushort4*)(xctx + (size_t)b * XC + IN + h0i) = o;
    }
}

// ---------------- LSTM pointwise ----------------
__device__ __forceinline__ float sigmf(float v) { return 1.0f / (1.0f + expf(-v)); }

__global__ __launch_bounds__(256) void lstm_pointwise_kernel(
    const float* __restrict__ g, const float* __restrict__ c_in,
    float* __restrict__ h_out, float* __restrict__ c_out,
    ushort* __restrict__ h_bf)
{
    int idx = blockIdx.x * 256 + threadIdx.x;
    int b = idx >> 10;
    int j = idx & 1023;
    const float* gr = g + (size_t)b * G4;
    float gi = gr[j];
    float gf = gr[j + H];
    float gc = gr[j + 2 * H];
    float go = gr[j + 3 * H];
    float c = sigmf(gf) * c_in[idx] + sigmf(gi) * tanhf(gc);
    float h = sigmf(go) * tanhf(c);
    h_out[idx] = h;
    c_out[idx] = c;
    if (h_bf) h_bf[idx] = f2bf(h);
}

// ---------------- pred ----------------
__global__ __launch_bounds__(256) void pred_kernel(
    const float* __restrict__ h2, const float* __restrict__ pw,
    const float* __restrict__ pb, float* __restrict__ out)
{
    int b = blockIdx.x;
    const float* row = h2 + (size_t)b * H;
    float s = 0.f;
    for (int j = threadIdx.x; j < H; j += 256) s += row[j] * pw[j];
    #pragma unroll
    for (int off = 32; off > 0; off >>= 1) s += __shfl_down(s, off, 64);
    __shared__ float sm[4];
    if ((threadIdx.x & 63) == 0) sm[threadIdx.x >> 6] = s;
    __syncthreads();
    if (threadIdx.x == 0) out[b] = sm[0] + sm[1] + sm[2] + sm[3] + pb[0];
}

extern "C" void kernel_launch(void* const* d_in, const int* in_sizes, int n_in,
                              void* d_out, int out_size, void* d_ws, size_t ws_size,
                              hipStream_t stream) {
    (void)in_sizes; (void)n_in; (void)out_size; (void)ws_size;
    const float* x      = (const float*)d_in[0];
    const int*   x_emb  = (const int*)d_in[1];
    const float* h0     = (const float*)d_in[2];
    const float* c0     = (const float*)d_in[3];
    const float* enc    = (const float*)d_in[4];
    const float* emb0   = (const float*)d_in[5];
    const float* emb1   = (const float*)d_in[6];
    const float* emb2   = (const float*)d_in[7];
    const float* emb3   = (const float*)d_in[8];
    const float* attn_w = (const float*)d_in[9];
    const float* attn_b = (const float*)d_in[10];
    const float* comb_w = (const float*)d_in[11];
    const float* comb_b = (const float*)d_in[12];
    const float* w_ih0  = (const float*)d_in[13];
    const float* w_hh0  = (const float*)d_in[14];
    const float* b_ih0  = (const float*)d_in[15];
    const float* b_hh0  = (const float*)d_in[16];
    const float* w_ih1  = (const float*)d_in[17];
    const float* w_hh1  = (const float*)d_in[18];
    const float* b_ih1  = (const float*)d_in[19];
    const float* b_hh1  = (const float*)d_in[20];
    const float* pred_w = (const float*)d_in[21];
    const float* pred_b = (const float*)d_in[22];

    float* out = (float*)d_out;
    const size_t BH = (size_t)B * H;
    float* h1_out = out + 1024;
    float* h2_out = out + 1024 + BH;
    float* c1_out = out + 1024 + 2 * BH;
    float* c2_out = out + 1024 + 3 * BH;
    float* aw_out = out + 1024 + 4 * BH;

    char* w = (char*)d_ws;
    ushort* attn_in_bf = (ushort*)w;  w += (size_t)B * AK * 2;
    ushort* h0_bf      = (ushort*)w;  w += (size_t)2 * BH * 2;
    ushort* attn_w_bf  = (ushort*)w;  w += (size_t)T * AK * 2;
    ushort* wih0_bf    = (ushort*)w;  w += (size_t)G4 * IN * 2;
    ushort* whh0_bf    = (ushort*)w;  w += (size_t)G4 * H * 2;
    ushort* wih1_bf    = (ushort*)w;  w += (size_t)G4 * H * 2;
    ushort* whh1_bf    = (ushort*)w;  w += (size_t)G4 * H * 2;
    ushort* comb_wT_bf = (ushort*)w;  w += (size_t)XC * IN * 2;
    ushort* W_f_bf     = (ushort*)w;  w += (size_t)G4 * XC * 2;
    float*  bias_f     = (float*)w;   w += (size_t)G4 * 4;
    ushort* xctx_bf    = (ushort*)w;  w += (size_t)B * XC * 2;
    ushort* h1_bf      = (ushort*)w;  w += (size_t)BH * 2;
    float*  logits_p   = (float*)w;   w += (size_t)4 * B * T * 4;
    float*  g1buf      = (float*)w;   w += (size_t)B * G4 * 4;
    float*  g2buf      = (float*)w;   w += (size_t)B * G4 * 4;
    // total ~93 MB

    convert_all_kernel<<<(CNT + 255) / 256, 256, 0, stream>>>(
        h0, attn_w, w_ih0, w_hh0, w_ih1, w_hh1,
        h0_bf, attn_w_bf, wih0_bf, whh0_bf, wih1_bf, whh1_bf);

    transpose_combw_kernel<<<(XC * IN) / 256, 256, 0, stream>>>(comb_w, comb_wT_bf);

    bias_f_kernel<<<G4 / 256, 256, 0, stream>>>(w_ih0, comb_b, b_ih0, b_hh0, bias_f);

    build_attn_in_kernel<<<B, 256, 0, stream>>>(x, x_emb, h0, c0, emb0, emb1, emb2, emb3,
                                                attn_in_bf, xctx_bf);

    // logits partials: split-K=4 over K=2176 (chunk 544)
    gemm_kernel<<<dim3(T / TN, B / TM, 4), 256, 0, stream>>>(
        attn_in_bf, attn_w_bf, nullptr, nullptr, nullptr, logits_p, nullptr,
        544, AK, AK, T, (size_t)B * T);

    // MEGA: hh0 + hh1 + W_f GEMMs interleaved with ctx (+softmax)
    mega_kernel<<<1824, 256, 0, stream>>>(
        h0_bf, whh0_bf, whh1_bf, g1buf, g2buf,
        wih0_bf, comb_wT_bf, W_f_bf,
        logits_p, attn_b, aw_out, enc, xctx_bf);

    // g1 = xctx @ W_f^T + g_hh0 + bias_f   (1024 x 4096, K=1152)
    gemm_kernel<<<dim3(G4 / TN, B / TM, 1), 256, 0, stream>>>(
        xctx_bf, W_f_bf, bias_f, nullptr, g1buf, g1buf, nullptr,
        XC, XC, XC, G4, 0);

    lstm_pointwise_kernel<<<(B * H) / 256, 256, 0, stream>>>(g1buf, c0, h1_out, c1_out, h1_bf);

    // g2 = h1 @ w_ih1^T + g_hh1 + b_ih1 + b_hh1   (1024 x 4096, K=1024)
    gemm_kernel<<<dim3(G4 / TN, B / TM, 1), 256, 0, stream>>>(
        h1_bf, wih1_bf, b_ih1, b_hh1, g2buf, g2buf, nullptr,
        H, H, H, G4, 0);

    lstm_pointwise_kernel<<<(B * H) / 256, 256, 0, stream>>>(g2buf, c0 + BH, h2_out, c2_out, nullptr);

    pred_kernel<<<1024, 256, 0, stream>>>(h2_out, pred_w, pred_b, out);
}

// Round 6
// 609.592 us; speedup vs baseline: 1.5193x; 1.0858x over previous
//
#include <hip/hip_runtime.h>
#include <hip/hip_bf16.h>

#define B 1024
#define H 1024
#define T 512
#define NUM 44
#define IN 128
#define AK (IN + 2 * H)   // 2176
#define XC (IN + H)       // 1152
#define G4 (4 * H)        // 4096
#define BH ((size_t)B * H)

typedef __attribute__((ext_vector_type(8))) short s16x8;
typedef __attribute__((ext_vector_type(4))) float f32x4;

__device__ __forceinline__ unsigned short f2bf(float f) {
    unsigned u = __float_as_uint(f);
    unsigned r = (u + 0x7fffu + ((u >> 16) & 1u)) >> 16;
    return (unsigned short)r;
}

__device__ __forceinline__ void gload16(const ushort* g, ushort* l) {
    __builtin_amdgcn_global_load_lds(
        (const __attribute__((address_space(1))) void*)g,
        (__attribute__((address_space(3))) void*)l,
        16, 0, 0);
}

#define TM 128
#define TN 128
#define TK 32

// ---------------- TM=128 GEMM tile core: C = X@W^T [+Cin][+b1][+b2] ----------------
__device__ __forceinline__ void gemm_core(
    const ushort* __restrict__ X, const ushort* __restrict__ W,
    const float* __restrict__ bias1, const float* __restrict__ bias2,
    const float* __restrict__ Cin, float* __restrict__ Cf, ushort* __restrict__ Cb,
    int kbeg, int kend, int ldx, int ldw, int ldc,
    int m0, int n0, ushort (*As)[TK], ushort (*Bs)[TK])
{
    const int tid = threadIdx.x;
    const int lane = tid & 63;
    const int wid = tid >> 6;
    const int wm = wid >> 1, wn = wid & 1;
    const int srow = wid * 32 + (lane >> 2);
    const int skc  = (lane & 3) * 8;

    f32x4 acc[4][4] = {};

    for (int k0 = kbeg; k0 < kend; k0 += TK) {
        gload16(X + (size_t)(m0 + srow) * ldx + k0 + skc,      &As[wid * 32][0]);
        gload16(X + (size_t)(m0 + srow + 16) * ldx + k0 + skc, &As[wid * 32 + 16][0]);
        gload16(W + (size_t)(n0 + srow) * ldw + k0 + skc,      &Bs[wid * 32][0]);
        gload16(W + (size_t)(n0 + srow + 16) * ldw + k0 + skc, &Bs[wid * 32 + 16][0]);
        __syncthreads();

        s16x8 a[4], b[4];
        #pragma unroll
        for (int m = 0; m < 4; ++m)
            a[m] = *(const s16x8*)&As[wm * 64 + m * 16 + (lane & 15)][(lane >> 4) * 8];
        #pragma unroll
        for (int n = 0; n < 4; ++n)
            b[n] = *(const s16x8*)&Bs[wn * 64 + n * 16 + (lane & 15)][(lane >> 4) * 8];
        #pragma unroll
        for (int m = 0; m < 4; ++m)
            #pragma unroll
            for (int n = 0; n < 4; ++n)
                acc[m][n] = __builtin_amdgcn_mfma_f32_16x16x32_bf16(a[m], b[n], acc[m][n], 0, 0, 0);
        __syncthreads();
    }

    #pragma unroll
    for (int m = 0; m < 4; ++m) {
        #pragma unroll
        for (int n = 0; n < 4; ++n) {
            int col = n0 + wn * 64 + n * 16 + (lane & 15);
            float badd = (bias1 ? bias1[col] : 0.f) + (bias2 ? bias2[col] : 0.f);
            #pragma unroll
            for (int j = 0; j < 4; ++j) {
                int row = m0 + wm * 64 + m * 16 + (lane >> 4) * 4 + j;
                float v = acc[m][n][j] + badd;
                if (Cin) v += Cin[(size_t)row * ldc + col];
                if (Cf) Cf[(size_t)row * ldc + col] = v;
                if (Cb) Cb[(size_t)row * ldc + col] = f2bf(v);
            }
        }
    }
}

// ---------------- ALL independent GEMMs in one launch ----------------
// rid [0,128): logits split-K=4   [128,384): hh0   [384,640): hh1   [640,928): W_f
__global__ __launch_bounds__(256) void allgemms_kernel(
    const ushort* __restrict__ attn_in, const ushort* __restrict__ attn_w_bf,
    float* __restrict__ logits_p,
    const ushort* __restrict__ h0_bf,
    const ushort* __restrict__ whh0_bf, const ushort* __restrict__ whh1_bf,
    float* __restrict__ g1buf, float* __restrict__ g2buf,
    const ushort* __restrict__ wih0_bf, const ushort* __restrict__ comb_wT_bf,
    ushort* __restrict__ W_f_bf)
{
    __shared__ ushort As[TM][TK];
    __shared__ ushort Bs[TN][TK];
    const int rid = blockIdx.x;
    if (rid < 128) {
        int z = rid >> 5, t = rid & 31;
        int m0 = (t >> 2) * TM, n0 = (t & 3) * TN;
        gemm_core(attn_in, attn_w_bf, nullptr, nullptr, nullptr,
                  logits_p + (size_t)z * B * T, nullptr,
                  z * 544, z * 544 + 544, AK, AK, T, m0, n0, As, Bs);
    } else if (rid < 640) {
        int layer = (rid - 128) >> 8;
        int t = (rid - 128) & 255;
        int m0 = (t >> 5) * TM, n0 = (t & 31) * TN;
        gemm_core(h0_bf + (size_t)layer * BH, layer ? whh1_bf : whh0_bf,
                  nullptr, nullptr, nullptr, layer ? g2buf : g1buf, nullptr,
                  0, H, H, H, G4, m0, n0, As, Bs);
    } else {
        int t = rid - 640;
        int m0 = (t / 9) * TM, n0 = (t % 9) * TN;
        gemm_core(wih0_bf, comb_wT_bf, nullptr, nullptr, nullptr, nullptr, W_f_bf,
                  0, IN, IN, IN, XC, m0, n0, As, Bs);
    }
}

// ---------------- TM=64 x TN=128 GEMM (higher occupancy for serial tail) ----------------
__global__ __launch_bounds__(256) void gemm64_kernel(
    const ushort* __restrict__ X, const ushort* __restrict__ W,
    const float* __restrict__ bias1, const float* __restrict__ bias2,
    const float* __restrict__ Cin, float* __restrict__ Cf,
    int K, int ldx, int ldw, int ldc)
{
    __shared__ ushort As[64][TK];
    __shared__ ushort Bs[128][TK];
    const int tid = threadIdx.x;
    const int lane = tid & 63;
    const int wid = tid >> 6;
    const int wm = wid >> 1, wn = wid & 1;
    const int m0 = blockIdx.y * 64;
    const int n0 = blockIdx.x * 128;
    const int skc = (lane & 3) * 8;

    f32x4 acc[2][4] = {};

    for (int k0 = 0; k0 < K; k0 += TK) {
        gload16(X + (size_t)(m0 + wid * 16 + (lane >> 2)) * ldx + k0 + skc, &As[wid * 16][0]);
        gload16(W + (size_t)(n0 + wid * 32 + (lane >> 2)) * ldw + k0 + skc, &Bs[wid * 32][0]);
        gload16(W + (size_t)(n0 + wid * 32 + 16 + (lane >> 2)) * ldw + k0 + skc, &Bs[wid * 32 + 16][0]);
        __syncthreads();
        s16x8 a[2], b[4];
        #pragma unroll
        for (int m = 0; m < 2; ++m)
            a[m] = *(const s16x8*)&As[wm * 32 + m * 16 + (lane & 15)][(lane >> 4) * 8];
        #pragma unroll
        for (int n = 0; n < 4; ++n)
            b[n] = *(const s16x8*)&Bs[wn * 64 + n * 16 + (lane & 15)][(lane >> 4) * 8];
        #pragma unroll
        for (int m = 0; m < 2; ++m)
            #pragma unroll
            for (int n = 0; n < 4; ++n)
                acc[m][n] = __builtin_amdgcn_mfma_f32_16x16x32_bf16(a[m], b[n], acc[m][n], 0, 0, 0);
        __syncthreads();
    }

    #pragma unroll
    for (int m = 0; m < 2; ++m) {
        #pragma unroll
        for (int n = 0; n < 4; ++n) {
            int col = n0 + wn * 64 + n * 16 + (lane & 15);
            float badd = (bias1 ? bias1[col] : 0.f) + (bias2 ? bias2[col] : 0.f);
            #pragma unroll
            for (int j = 0; j < 4; ++j) {
                int row = m0 + wm * 32 + m * 16 + (lane >> 4) * 4 + j;
                float v = acc[m][n][j] + badd;
                if (Cin) v += Cin[(size_t)row * ldc + col];
                Cf[(size_t)row * ldc + col] = v;
            }
        }
    }
}

// ---------------- preamble: converts + comb_w transpose + bias_f + build ----------------
#define P0 2048            // h0 (f4)
#define P1 (P0 + 1088)     // attn_w
#define P2 (P1 + 512)      // w_ih0
#define P3 (P2 + 4096)     // w_hh0
#define P4 (P3 + 4096)     // w_ih1
#define P5 (P4 + 4096)     // w_hh1
#define P6 (P5 + 576)      // comb_w transpose
#define P7 (P6 + 16)       // bias_f
#define P8 (P7 + 1024)     // build attn_in

__global__ __launch_bounds__(256) void preamble_kernel(
    const float* __restrict__ h0, const float* __restrict__ attn_w,
    const float* __restrict__ w_ih0, const float* __restrict__ w_hh0,
    const float* __restrict__ w_ih1, const float* __restrict__ w_hh1,
    const float* __restrict__ comb_w, const float* __restrict__ comb_b,
    const float* __restrict__ b_ih0, const float* __restrict__ b_hh0,
    const float* __restrict__ x, const int* __restrict__ x_emb,
    const float* __restrict__ c0,
    const float* __restrict__ e0, const float* __restrict__ e1,
    const float* __restrict__ e2, const float* __restrict__ e3,
    ushort* __restrict__ h0_bf, ushort* __restrict__ attn_w_bf,
    ushort* __restrict__ wih0_bf, ushort* __restrict__ whh0_bf,
    ushort* __restrict__ wih1_bf, ushort* __restrict__ whh1_bf,
    ushort* __restrict__ comb_wT, float* __restrict__ biasf,
    ushort* __restrict__ attn_in, ushort* __restrict__ xctx)
{
    const int bid = blockIdx.x;
    const int tid = threadIdx.x;

    if (bid < P5) {
        const float* s; ushort* d; int f;
        if (bid < P0)      { f = bid * 256 + tid;        s = h0;     d = h0_bf; }
        else if (bid < P1) { f = (bid - P0) * 256 + tid; s = attn_w; d = attn_w_bf; }
        else if (bid < P2) { f = (bid - P1) * 256 + tid; s = w_ih0;  d = wih0_bf; }
        else if (bid < P3) { f = (bid - P2) * 256 + tid; s = w_hh0;  d = whh0_bf; }
        else if (bid < P4) { f = (bid - P3) * 256 + tid; s = w_ih1;  d = wih1_bf; }
        else               { f = (bid - P4) * 256 + tid; s = w_hh1;  d = whh1_bf; }
        float4 v = ((const float4*)s)[f];
        ushort4 o = {f2bf(v.x), f2bf(v.y), f2bf(v.z), f2bf(v.w)};
        ((ushort4*)d)[f] = o;
    } else if (bid < P6) {
        int e = (bid - P5) * 256 + tid;      // comb_wT[j*128+k] = comb_w[k][j]
        int j = e >> 7, k = e & 127;
        comb_wT[e] = f2bf(comb_w[(size_t)k * XC + j]);
    } else if (bid < P7) {
        __shared__ float cb[IN];
        for (int i = tid; i < IN; i += 256) cb[i] = comb_b[i];
        __syncthreads();
        int i = (bid - P6) * 256 + tid;
        float s = b_ih0[i] + b_hh0[i];
        const float* row = w_ih0 + (size_t)i * IN;
        #pragma unroll 8
        for (int j = 0; j < IN; ++j) s += row[j] * cb[j];
        biasf[i] = s;
    } else {
        int b = bid - P7;
        int id0 = x_emb[b * 4 + 0];
        int id1 = x_emb[b * 4 + 1];
        int id2 = x_emb[b * 4 + 2];
        int id3 = x_emb[b * 4 + 3];
        ushort* dst = attn_in + (size_t)b * AK;
        for (int j = tid; j < AK; j += 256) {
            float v;
            if (j < 44)        v = x[b * NUM + j];
            else if (j < 108)  v = e0[id0 * 64 + (j - 44)];
            else if (j < 116)  v = e1[id1 * 8 + (j - 108)];
            else if (j < 124)  v = e2[id2 * 8 + (j - 116)];
            else if (j < 128)  v = e3[id3 * 4 + (j - 124)];
            else if (j < 1152) v = h0[b * H + (j - 128)];
            else               v = c0[b * H + (j - 1152)];
            unsigned short bf = f2bf(v);
            dst[j] = bf;
            if (j < IN) xctx[(size_t)b * XC + j] = bf;
        }
    }
}

// ---------------- ctx stream: t-split x2, 16-deep load batches ----------------
// 2048 blocks: b = bid>>1, z = bid&1 (t range [z*256, z*256+256)).
// Both halves redundantly compute softmax; z=0 writes aw_out. Partials -> ctxp[z].
__global__ __launch_bounds__(256) void ctx_kernel(
    const float* __restrict__ enc, const float* __restrict__ logits_p,
    const float* __restrict__ attn_b, float* __restrict__ aw_out,
    float* __restrict__ ctxp)
{
    const int b = blockIdx.x >> 1;
    const int z = blockIdx.x & 1;
    const int tid = threadIdx.x;
    __shared__ float w[T];
    __shared__ float red[8];

    float v0 = attn_b[tid], v1 = attn_b[tid + 256];
    #pragma unroll
    for (int q = 0; q < 4; ++q) {
        const float* lp = logits_p + (size_t)q * B * T + (size_t)b * T;
        v0 += lp[tid];
        v1 += lp[tid + 256];
    }
    float m = fmaxf(v0, v1);
    #pragma unroll
    for (int off = 32; off > 0; off >>= 1) m = fmaxf(m, __shfl_down(m, off, 64));
    if ((tid & 63) == 0) red[tid >> 6] = m;
    __syncthreads();
    m = fmaxf(fmaxf(red[0], red[1]), fmaxf(red[2], red[3]));
    float e0 = expf(v0 - m), e1 = expf(v1 - m);
    float s = e0 + e1;
    #pragma unroll
    for (int off = 32; off > 0; off >>= 1) s += __shfl_down(s, off, 64);
    if ((tid & 63) == 0) red[4 + (tid >> 6)] = s;
    __syncthreads();
    s = red[4] + red[5] + red[6] + red[7];
    float inv = 1.0f / s;
    float w0 = e0 * inv, w1 = e1 * inv;
    w[tid] = w0;
    w[tid + 256] = w1;
    if (z == 0) {
        aw_out[(size_t)b * T + tid]       = w0;
        aw_out[(size_t)b * T + tid + 256] = w1;
    }
    __syncthreads();

    const float* p = enc + (size_t)(z * 256) * B * H + (size_t)b * H + tid * 4;
    float4 acc = {0.f, 0.f, 0.f, 0.f};
    for (int t0 = 0; t0 < 256; t0 += 16) {
        float4 vv[16];
        #pragma unroll
        for (int u = 0; u < 16; ++u)
            vv[u] = *(const float4*)(p + (size_t)(t0 + u) * B * H);
        #pragma unroll
        for (int u = 0; u < 16; ++u) {
            float sw = w[z * 256 + t0 + u];
            acc.x += sw * vv[u].x; acc.y += sw * vv[u].y;
            acc.z += sw * vv[u].z; acc.w += sw * vv[u].w;
        }
    }
    *(float4*)(ctxp + (size_t)z * BH + (size_t)b * H + tid * 4) = acc;
}

// ---------------- ctx partial reduce -> xctx bf16 ----------------
__global__ __launch_bounds__(256) void ctx_reduce_kernel(
    const float* __restrict__ ctxp, ushort* __restrict__ xctx)
{
    int i = blockIdx.x * 256 + threadIdx.x;   // f4 index over BH/4
    float4 a = ((const float4*)ctxp)[i];
    float4 c = ((const float4*)(ctxp + BH))[i];
    int f = i * 4;
    int b = f >> 10, h = f & 1023;
    ushort4 o = {f2bf(a.x + c.x), f2bf(a.y + c.y), f2bf(a.z + c.z), f2bf(a.w + c.w)};
    *(ushort4*)(xctx + (size_t)b * XC + IN + h) = o;
}

// ---------------- LSTM pointwise ----------------
__device__ __forceinline__ float sigmf(float v) { return 1.0f / (1.0f + expf(-v)); }

__global__ __launch_bounds__(256) void lstm_pointwise_kernel(
    const float* __restrict__ g, const float* __restrict__ c_in,
    float* __restrict__ h_out, float* __restrict__ c_out,
    ushort* __restrict__ h_bf)
{
    int idx = blockIdx.x * 256 + threadIdx.x;
    int b = idx >> 10;
    int j = idx & 1023;
    const float* gr = g + (size_t)b * G4;
    float gi = gr[j];
    float gf = gr[j + H];
    float gc = gr[j + 2 * H];
    float go = gr[j + 3 * H];
    float c = sigmf(gf) * c_in[idx] + sigmf(gi) * tanhf(gc);
    float h = sigmf(go) * tanhf(c);
    h_out[idx] = h;
    c_out[idx] = c;
    if (h_bf) h_bf[idx] = f2bf(h);
}

// ---------------- pred ----------------
__global__ __launch_bounds__(256) void pred_kernel(
    const float* __restrict__ h2, const float* __restrict__ pw,
    const float* __restrict__ pb, float* __restrict__ out)
{
    int b = blockIdx.x;
    const float* row = h2 + (size_t)b * H;
    float s = 0.f;
    for (int j = threadIdx.x; j < H; j += 256) s += row[j] * pw[j];
    #pragma unroll
    for (int off = 32; off > 0; off >>= 1) s += __shfl_down(s, off, 64);
    __shared__ float sm[4];
    if ((threadIdx.x & 63) == 0) sm[threadIdx.x >> 6] = s;
    __syncthreads();
    if (threadIdx.x == 0) out[b] = sm[0] + sm[1] + sm[2] + sm[3] + pb[0];
}

extern "C" void kernel_launch(void* const* d_in, const int* in_sizes, int n_in,
                              void* d_out, int out_size, void* d_ws, size_t ws_size,
                              hipStream_t stream) {
    (void)in_sizes; (void)n_in; (void)out_size; (void)ws_size;
    const float* x      = (const float*)d_in[0];
    const int*   x_emb  = (const int*)d_in[1];
    const float* h0     = (const float*)d_in[2];
    const float* c0     = (const float*)d_in[3];
    const float* enc    = (const float*)d_in[4];
    const float* emb0   = (const float*)d_in[5];
    const float* emb1   = (const float*)d_in[6];
    const float* emb2   = (const float*)d_in[7];
    const float* emb3   = (const float*)d_in[8];
    const float* attn_w = (const float*)d_in[9];
    const float* attn_b = (const float*)d_in[10];
    const float* comb_w = (const float*)d_in[11];
    const float* comb_b = (const float*)d_in[12];
    const float* w_ih0  = (const float*)d_in[13];
    const float* w_hh0  = (const float*)d_in[14];
    const float* b_ih0  = (const float*)d_in[15];
    const float* b_hh0  = (const float*)d_in[16];
    const float* w_ih1  = (const float*)d_in[17];
    const float* w_hh1  = (const float*)d_in[18];
    const float* b_ih1  = (const float*)d_in[19];
    const float* b_hh1  = (const float*)d_in[20];
    const float* pred_w = (const float*)d_in[21];
    const float* pred_b = (const float*)d_in[22];

    float* out = (float*)d_out;
    float* h1_out = out + 1024;
    float* h2_out = out + 1024 + BH;
    float* c1_out = out + 1024 + 2 * BH;
    float* c2_out = out + 1024 + 3 * BH;
    float* aw_out = out + 1024 + 4 * BH;

    char* w = (char*)d_ws;
    ushort* attn_in_bf = (ushort*)w;  w += (size_t)B * AK * 2;        // dead after allgemms
    ushort* h0_bf      = (ushort*)w;  w += (size_t)2 * BH * 2;        // dead after allgemms
    ushort* attn_w_bf  = (ushort*)w;  w += (size_t)T * AK * 2;
    ushort* wih0_bf    = (ushort*)w;  w += (size_t)G4 * IN * 2;
    ushort* whh0_bf    = (ushort*)w;  w += (size_t)G4 * H * 2;
    ushort* wih1_bf    = (ushort*)w;  w += (size_t)G4 * H * 2;
    ushort* whh1_bf    = (ushort*)w;  w += (size_t)G4 * H * 2;
    ushort* comb_wT_bf = (ushort*)w;  w += (size_t)XC * IN * 2;
    ushort* W_f_bf     = (ushort*)w;  w += (size_t)G4 * XC * 2;
    float*  bias_f     = (float*)w;   w += (size_t)G4 * 4;
    ushort* xctx_bf    = (ushort*)w;  w += (size_t)B * XC * 2;
    ushort* h1_bf      = (ushort*)w;  w += (size_t)BH * 2;
    float*  logits_p   = (float*)w;   w += (size_t)4 * B * T * 4;
    float*  g1buf      = (float*)w;   w += (size_t)B * G4 * 4;
    float*  g2buf      = (float*)w;   w += (size_t)B * G4 * 4;
    // ctxp (2*BH f32 = 8 MB) aliases attn_in_bf + h0_bf (both dead before ctx launches)
    float*  ctxp       = (float*)d_ws;

    preamble_kernel<<<P8, 256, 0, stream>>>(
        h0, attn_w, w_ih0, w_hh0, w_ih1, w_hh1, comb_w, comb_b, b_ih0, b_hh0,
        x, x_emb, c0, emb0, emb1, emb2, emb3,
        h0_bf, attn_w_bf, wih0_bf, whh0_bf, wih1_bf, whh1_bf, comb_wT_bf, bias_f,
        attn_in_bf, xctx_bf);

    // logits (split-K 4) + hh0 + hh1 + W_f : one launch, 928 blocks
    allgemms_kernel<<<928, 256, 0, stream>>>(
        attn_in_bf, attn_w_bf, logits_p,
        h0_bf, whh0_bf, whh1_bf, g1buf, g2buf,
        wih0_bf, comb_wT_bf, W_f_bf);

    // enc stream: softmax + weighted sum, t-split x2
    ctx_kernel<<<2048, 256, 0, stream>>>(enc, logits_p, attn_b, aw_out, ctxp);

    ctx_reduce_kernel<<<(int)(BH / 4 / 256), 256, 0, stream>>>(ctxp, xctx_bf);

    // g1 = xctx @ W_f^T + g1buf + bias_f   (K=1152), 512 blocks
    gemm64_kernel<<<dim3(G4 / 128, B / 64), 256, 0, stream>>>(
        xctx_bf, W_f_bf, bias_f, nullptr, g1buf, g1buf, XC, XC, XC, G4);

    lstm_pointwise_kernel<<<(int)(BH / 256), 256, 0, stream>>>(g1buf, c0, h1_out, c1_out, h1_bf);

    // g2 = h1 @ w_ih1^T + g2buf + b_ih1 + b_hh1   (K=1024), 512 blocks
    gemm64_kernel<<<dim3(G4 / 128, B / 64), 256, 0, stream>>>(
        h1_bf, wih1_bf, b_ih1, b_hh1, g2buf, g2buf, H, H, H, G4);

    lstm_pointwise_kernel<<<(int)(BH / 256), 256, 0, stream>>>(g2buf, c0 + BH, h2_out, c2_out, nullptr);

    pred_kernel<<<1024, 256, 0, stream>>>(h2_out, pred_w, pred_b, out);
}